// Round 2
// baseline (360.716 us; speedup 1.0000x reference)
//
#include <hip/hip_runtime.h>

#define EPS 1e-6f
#define LN2F 0.69314718055994530942f

// ============================================================================
// Phase A: pure streaming. 2048 blocks x 256 thr = 8192 waves, grid-stride
// over 1024-element tiles. Per tile: 12 coalesced float4 loads held in NAMED
// scalars (no arrays -> no scratch possible), per-element wbce accumulated in
// a per-lane register, correctness nibbles transposed wave-privately through
// LDS so each lane emits one 16-bit mask covering 16 CONTIGUOUS elements
// (1 ushort store). No cross-lane reduce, no block barrier in the hot loop.
// ============================================================================

#define ONE(pc, tc, wc, bit) {                                   \
    const bool  tb  = (tc) != 0.0f;  /* y_true is exactly 0/1 */ \
    const float sel = tb ? (pc) : 1.0f - (pc);                   \
    sum = fmaf((wc), __log2f(sel + EPS), sum);                   \
    nibs |= (unsigned)(((pc) > 0.5f) == tb) << (bit); }

#define CHUNK(P, T, W, q) {                  \
    ONE(P.x, T.x, W.x, 8*(q)+0)              \
    ONE(P.y, T.y, W.y, 8*(q)+1)              \
    ONE(P.z, T.z, W.z, 8*(q)+2)              \
    ONE(P.w, T.w, W.w, 8*(q)+3) }

__global__ __launch_bounds__(256, 4) void phaseA_kernel(
        const float* __restrict__ yp, const float* __restrict__ yt,
        const float* __restrict__ dw,
        unsigned short* __restrict__ masks,   // one ushort per 16 elements
        float* __restrict__ wv_wbce,          // one partial per wave (8192)
        long tiles_total) {
    const int lane = threadIdx.x & 63;
    const int wave = threadIdx.x >> 6;
    const long wgid = (long)blockIdx.x * 4 + wave;
    const long nwv  = (long)gridDim.x * 4;

    __shared__ unsigned nibbuf[256];          // wave-private 64-dword segments

    float sum = 0.0f;                         // raw sum of w * log2(sel + eps)

    for (long t = wgid; t < tiles_total; t += nwv) {
        const long base = t * 1024 + lane * 4;
        const float4* pp = (const float4*)(yp + base);
        const float4* tp = (const float4*)(yt + base);
        const float4* wp = (const float4*)(dw + base);

        // 12 independent, perfectly coalesced loads (1KB/wave-inst), all
        // issued before first use. Named scalars: cannot go to scratch.
        const float4 p0 = pp[0],   p1 = pp[64],  p2 = pp[128], p3 = pp[192];
        const float4 t0 = tp[0],   t1 = tp[64],  t2 = tp[128], t3 = tp[192];
        const float4 w0 = wp[0],   w1 = wp[64],  w2 = wp[128], w3 = wp[192];

        unsigned nibs = 0;                    // byte q = correctness nibble
        CHUNK(p0, t0, w0, 0)
        CHUNK(p1, t1, w1, 1)
        CHUNK(p2, t2, w2, 2)
        CHUNK(p3, t3, w3, 3)

        // wave-private nibble transpose: 1 dword write + 1 b128 read
        nibbuf[wave * 64 + lane] = nibs;
        asm volatile("s_waitcnt lgkmcnt(0)" ::: "memory");
        const uint4 d = *(const uint4*)&nibbuf[wave * 64 + 4 * (lane & 15)];
        const int qs = (lane >> 4) * 8;
        const unsigned mask = ((d.x >> qs) & 0xFu)
                            | (((d.y >> qs) & 0xFu) << 4)
                            | (((d.z >> qs) & 0xFu) << 8)
                            | (((d.w >> qs) & 0xFu) << 12);
        // lane's 16 bits cover elements [t*1024 + (lane>>4)*256 + (lane&15)*16, +16)
        masks[t * 64 + (lane >> 4) * 16 + (lane & 15)] = (unsigned short)mask;
    }

    // one butterfly per wave for the whole kernel (amortized to ~0)
    #pragma unroll
    for (int off = 32; off; off >>= 1) sum += __shfl_down(sum, off);
    if (lane == 0) wv_wbce[wgid] = sum;
}

// ============================================================================
// Phase B: per-row max streak from masks. Row = 256 ushorts = 4KB bits; lane
// reads one aligned uint64 (64 contiguous elements), computes RunStats via a
// 64-bit doubling ladder, then a 6-step ordered shuffle combine. 256 blocks
// x 4 waves = 1024 waves, 8 rows each; per-wave streak sums -> workspace.
// ============================================================================
__global__ __launch_bounds__(256, 4) void phaseB_kernel(
        const unsigned short* __restrict__ masks,
        int* __restrict__ wv_streak, long rows) {
    const int lane = threadIdx.x & 63;
    const int wave = threadIdx.x >> 6;
    const long wgid = (long)blockIdx.x * 4 + wave;
    const long nwv  = (long)gridDim.x * 4;

    int acc = 0;
    for (long r = wgid; r < rows; r += nwv) {
        const unsigned long long m =
            *(const unsigned long long*)(masks + r * 256 + lane * 4);
        int pre, suf, mx;
        if (~m == 0ULL) {
            pre = suf = mx = 64;
        } else {
            pre = __builtin_ctzll(~m);            // leading-run (bit0 = first elem)
            suf = __builtin_clzll(~m);            // trailing-run (top bits)
            const unsigned long long pp1 = m;
            const unsigned long long pp2 = pp1 & (pp1 << 1);
            const unsigned long long pp4 = pp2 & (pp2 << 2);
            const unsigned long long pp8 = pp4 & (pp4 << 4);
            const unsigned long long pp16 = pp8 & (pp8 << 8);
            const unsigned long long pp32 = pp16 & (pp16 << 16);
            unsigned long long z; int len;
            if (pp32)      { z = pp32; len = 32; }
            else if (pp16) { z = pp16; len = 16; }
            else if (pp8)  { z = pp8;  len = 8; }
            else if (pp4)  { z = pp4;  len = 4; }
            else if (pp2)  { z = pp2;  len = 2; }
            else           { z = pp1;  len = 1; }
            { const unsigned long long q = (z << 16) & pp16; if (q) { z = q; len += 16; } }
            { const unsigned long long q = (z << 8)  & pp8;  if (q) { z = q; len += 8; } }
            { const unsigned long long q = (z << 4)  & pp4;  if (q) { z = q; len += 4; } }
            { const unsigned long long q = (z << 2)  & pp2;  if (q) { z = q; len += 2; } }
            { const unsigned long long q = (z << 1)  & pp1;  if (q) { z = q; len += 1; } }
            mx = m ? len : 0;
        }

        // ordered combine across 64 lanes (lane order == element order)
        int alen = 64;
        #pragma unroll
        for (int off = 1; off < 64; off <<= 1) {
            const int bpre = __shfl_down(pre, off);
            const int bsuf = __shfl_down(suf, off);
            const int bmx  = __shfl_down(mx,  off);
            const int npre = (pre == alen) ? (alen + bpre) : pre;
            const int nsuf = (bsuf == alen) ? (alen + suf) : bsuf;
            mx  = max(max(mx, bmx), suf + bpre);
            pre = npre; suf = nsuf; alen <<= 1;
        }
        if (lane == 0) acc += mx;             // row max-streak
    }
    if (lane == 0) wv_streak[wgid] = acc;
}

// ============================================================================
// Finalize: sum 8192 wbce partials (double) + 1024 streak partials.
// ============================================================================
__global__ __launch_bounds__(1024) void finalize_kernel(
        const float* __restrict__ wv_wbce, int nA,
        const int* __restrict__ wv_streak, int nB,
        long long total_elems, float* __restrict__ out) {
    double s = 0.0;
    long long st = 0;
    for (int i = threadIdx.x; i < nA; i += 1024) s  += (double)wv_wbce[i];
    for (int i = threadIdx.x; i < nB; i += 1024) st += (long long)wv_streak[i];
    __shared__ double sd[1024];
    __shared__ long long sl[1024];
    sd[threadIdx.x] = s; sl[threadIdx.x] = st;
    __syncthreads();
    for (int o = 512; o; o >>= 1) {
        if (threadIdx.x < o) {
            sd[threadIdx.x] += sd[threadIdx.x + o];
            sl[threadIdx.x] += sl[threadIdx.x + o];
        }
        __syncthreads();
    }
    if (threadIdx.x == 0) {
        const double total = (double)total_elems;
        const double wbce = -LN2F * sd[0] / total;
        const double cwl  = 1.0 - (double)sl[0] / total;
        out[0] = (float)(0.5 * wbce + 0.5 * cwl);
    }
}

// ============================================================================
// Fallback (ws too small): round-0 proven single-pass kernel.
// ============================================================================
struct RunStats { int len, pre, suf, mx; };
__device__ inline RunStats rcombine(const RunStats& a, const RunStats& b) {
    RunStats r;
    r.len = a.len + b.len;
    r.pre = (a.pre == a.len) ? (a.len + b.pre) : a.pre;
    r.suf = (b.suf == b.len) ? (b.len + a.suf) : b.suf;
    r.mx  = max(max(a.mx, b.mx), a.suf + b.pre);
    return r;
}

__global__ __launch_bounds__(256) void fb_row_kernel(
        const float* __restrict__ yp, const float* __restrict__ yt,
        const float* __restrict__ dw,
        float* __restrict__ row_wbce, int* __restrict__ row_streak) {
    const int row  = blockIdx.x;
    const int lane = threadIdx.x & 63;
    const int wave = threadIdx.x >> 6;
    const long base = (long)row * 4096 + wave * 1024 + lane * 4;
    const float4* pp = (const float4*)(yp + base);
    const float4* tp = (const float4*)(yt + base);
    const float4* wp = (const float4*)(dw + base);

    float sum = 0.0f;
    unsigned nibs = 0;
    #pragma unroll
    for (int q = 0; q < 4; ++q) {
        const float4 P = pp[q * 64];
        const float4 T = tp[q * 64];
        const float4 W = wp[q * 64];
        CHUNK(P, T, W, q)
    }
    __shared__ unsigned nibbuf[256];
    nibbuf[wave * 64 + lane] = nibs;
    __syncthreads();
    const uint4 d = *(const uint4*)&nibbuf[wave * 64 + 4 * (lane & 15)];
    const int qs = (lane >> 4) * 8;
    const unsigned mask = ((d.x >> qs) & 0xFu) | (((d.y >> qs) & 0xFu) << 4)
                        | (((d.z >> qs) & 0xFu) << 8) | (((d.w >> qs) & 0xFu) << 12);
    const int pre = __builtin_ctz(~mask);
    const int suf = __builtin_clz(~(mask << 16));
    int mx;
    {
        const unsigned p1 = mask, p2 = p1 & (p1 << 1), p4 = p2 & (p2 << 2), p8 = p4 & (p4 << 4);
        unsigned z; int len;
        if (p8) { z = p8; len = 8; } else if (p4) { z = p4; len = 4; }
        else if (p2) { z = p2; len = 2; } else { z = p1; len = 1; }
        { const unsigned q2 = (z << 8) & p8; if (q2) { z = q2; len += 8; } }
        { const unsigned q2 = (z << 4) & p4; if (q2) { z = q2; len += 4; } }
        { const unsigned q2 = (z << 2) & p2; if (q2) { z = q2; len += 2; } }
        { const unsigned q2 = (z << 1) & p1; if (q2) { z = q2; len += 1; } }
        mx = mask ? len : 0;
    }
    #pragma unroll
    for (int off = 32; off; off >>= 1) sum += __shfl_down(sum, off);
    int packed = pre | (suf << 10) | (mx << 20);
    int alen = 16;
    #pragma unroll
    for (int off = 1; off < 32; off <<= 1) {
        const int o = __shfl_down(packed, off);
        const int apre = packed & 1023, asuf = (packed >> 10) & 1023, amx = packed >> 20;
        const int bpre = o & 1023, bsuf = (o >> 10) & 1023, bmx = o >> 20;
        packed = ((apre == alen) ? (alen + bpre) : apre)
               | (((bsuf == alen) ? (alen + asuf) : bsuf) << 10)
               | (max(max(amx, bmx), asuf + bpre) << 20);
        alen <<= 1;
    }
    RunStats g;
    {
        const int o = __shfl_down(packed, 32);
        const int apre = packed & 1023, asuf = (packed >> 10) & 1023, amx = packed >> 20;
        const int bpre = o & 1023, bsuf = (o >> 10) & 1023, bmx = o >> 20;
        g.len = 1024;
        g.pre = (apre == 512) ? (512 + bpre) : apre;
        g.suf = (bsuf == 512) ? (512 + asuf) : bsuf;
        g.mx  = max(max(amx, bmx), asuf + bpre);
    }
    __shared__ RunStats sstat[4];
    __shared__ float ssum[4];
    if (lane == 0) { sstat[wave] = g; ssum[wave] = sum; }
    __syncthreads();
    if (threadIdx.x == 0) {
        RunStats r = rcombine(rcombine(sstat[0], sstat[1]), rcombine(sstat[2], sstat[3]));
        row_wbce[row]   = -LN2F * (ssum[0] + ssum[1] + ssum[2] + ssum[3]);
        row_streak[row] = r.mx;
    }
}

__global__ __launch_bounds__(1024) void fb_finalize_kernel(
        const float* __restrict__ row_wbce, const int* __restrict__ row_streak,
        int rows, float* __restrict__ out) {
    double s = 0.0; long long st = 0;
    for (int i = threadIdx.x; i < rows; i += 1024) {
        s += (double)row_wbce[i]; st += (long long)row_streak[i];
    }
    __shared__ double sd[1024];
    __shared__ long long sl[1024];
    sd[threadIdx.x] = s; sl[threadIdx.x] = st;
    __syncthreads();
    for (int o = 512; o; o >>= 1) {
        if (threadIdx.x < o) { sd[threadIdx.x] += sd[threadIdx.x + o]; sl[threadIdx.x] += sl[threadIdx.x + o]; }
        __syncthreads();
    }
    if (threadIdx.x == 0) {
        const double total = (double)rows * 4096.0;
        out[0] = (float)(0.5 * (sd[0] / total) + 0.5 * (1.0 - (double)sl[0] / total));
    }
}

extern "C" void kernel_launch(void* const* d_in, const int* in_sizes, int n_in,
                              void* d_out, int out_size, void* d_ws, size_t ws_size,
                              hipStream_t stream) {
    const float* yp = (const float*)d_in[0];
    const float* yt = (const float*)d_in[1];
    const float* dw = (const float*)d_in[2];
    float* out = (float*)d_out;

    const long rows = in_sizes[0] / 4096;             // 8192
    const long long total = (long long)rows * 4096;

    const size_t mask_bytes = (size_t)rows * 512;     // rows*256 ushorts
    const size_t off_wbce   = mask_bytes;             // 8192 floats
    const size_t off_streak = off_wbce + 8192 * sizeof(float);
    const size_t need       = off_streak + 1024 * sizeof(int);

    if (ws_size >= need) {
        unsigned short* masks  = (unsigned short*)d_ws;
        float* wv_wbce         = (float*)((char*)d_ws + off_wbce);
        int*   wv_streak       = (int*)((char*)d_ws + off_streak);
        const long tiles_total = total / 1024;

        phaseA_kernel<<<2048, 256, 0, stream>>>(yp, yt, dw, masks, wv_wbce, tiles_total);
        phaseB_kernel<<<256, 256, 0, stream>>>(masks, wv_streak, rows);
        finalize_kernel<<<1, 1024, 0, stream>>>(wv_wbce, 8192, wv_streak, 1024, total, out);
    } else {
        float* row_wbce   = (float*)d_ws;
        int*   row_streak = (int*)((char*)d_ws + (size_t)rows * sizeof(float));
        fb_row_kernel<<<(int)rows, 256, 0, stream>>>(yp, yt, dw, row_wbce, row_streak);
        fb_finalize_kernel<<<1, 1024, 0, stream>>>(row_wbce, row_streak, (int)rows, out);
    }
}